// Round 10
// baseline (789.365 us; speedup 1.0000x reference)
//
#include <hip/hip_runtime.h>
#include <hip/hip_bf16.h>

typedef __bf16 v8bf __attribute__((ext_vector_type(8)));
typedef float  f32x4 __attribute__((ext_vector_type(4)));
typedef unsigned short us4 __attribute__((ext_vector_type(4)));
typedef unsigned short us8 __attribute__((ext_vector_type(8)));

#define KVOL 27
#define KG   4       // taps staged to LDS per group
#define NBKT 16384   // sort buckets
#define SCB  2048    // scan block elements

__device__ __forceinline__ unsigned short f2bf(float f) {
    unsigned int u = __float_as_uint(f);
    u = u + 0x7FFFu + ((u >> 16) & 1u);   // round-to-nearest-even
    return (unsigned short)(u >> 16);
}
__device__ __forceinline__ float bf2f(unsigned short u) {
    return __uint_as_float((unsigned int)u << 16);
}

// ---------------------------------------------------------------------------
// Prep: W -> bf16 MFMA fragments; zero stats[128].
// ---------------------------------------------------------------------------
__global__ __launch_bounds__(256) void prep_kernel(const float* __restrict__ W,
                                                   unsigned short* __restrict__ wfrag,
                                                   float* __restrict__ stats) {
    if (blockIdx.x == 0 && threadIdx.x < 128) stats[threadIdx.x] = 0.0f;
    int d = blockIdx.x * 256 + threadIdx.x;
    if (d < KVOL * 64 * 64) {
        int i    = d & 7;
        int lane = (d >> 3) & 63;
        int s    = (d >> 9) & 1;
        int t    = (d >> 10) & 3;
        int k    = d >> 12;
        int kin  = s * 32 + (lane >> 4) * 8 + i;
        int c    = t * 16 + (lane & 15);
        wfrag[d] = f2bf(W[k * 4096 + kin * 64 + c]);
    }
}

// Histogram of points by center-tap output row (output-order proxy).
__global__ __launch_bounds__(256) void hist_kernel(const int* __restrict__ oidx,
                                                   int* __restrict__ hist,
                                                   int Npts, int Nout) {
    for (int p = blockIdx.x * 256 + threadIdx.x; p < Npts; p += gridDim.x * 256) {
        int o = oidx[p * KVOL + 13];
        int b = (int)(((long long)o * NBKT) / Nout);
        atomicAdd(&hist[b], 1);
    }
}

// In-place exclusive scan of hist[NBKT].
__global__ __launch_bounds__(256) void scan_hist(int* __restrict__ hist) {
    __shared__ int ts[256];
    const int tid  = threadIdx.x;
    const int base = tid * 64;
    int s = 0;
    for (int i = 0; i < 64; ++i) s += hist[base + i];
    ts[tid] = s;
    __syncthreads();
    if (tid == 0) {
        int run = 0;
        for (int i = 0; i < 256; ++i) { int v = ts[i]; ts[i] = run; run += v; }
    }
    __syncthreads();
    int run = ts[tid];
    for (int i = 0; i < 64; ++i) { int v = hist[base + i]; hist[base + i] = run; run += v; }
}

// perm: points grouped by bucket (approximately output-sorted).
__global__ __launch_bounds__(256) void perm_fill(const int* __restrict__ oidx,
                                                 int* __restrict__ cursor,
                                                 int* __restrict__ perm,
                                                 int Npts, int Nout) {
    for (int p = blockIdx.x * 256 + threadIdx.x; p < Npts; p += gridDim.x * 256) {
        int o = oidx[p * KVOL + 13];
        int b = (int)(((long long)o * NBKT) / Nout);
        int pos = atomicAdd(&cursor[b], 1);
        perm[pos] = p;
    }
}

__global__ __launch_bounds__(256) void count_kernel(const int* __restrict__ oidx,
                                                    int* __restrict__ cnt, int M) {
    for (int e = blockIdx.x * 256 + threadIdx.x; e < M; e += gridDim.x * 256)
        atomicAdd(&cnt[oidx[e]], 1);
}

// ------------------------- CSR scan (3 phases) -----------------------------
__global__ __launch_bounds__(256) void scan_part(const int* __restrict__ cnt,
                                                 int* __restrict__ psums, int Nout) {
    __shared__ int ts[256];
    const int b = blockIdx.x, t = threadIdx.x;
    int s = 0;
    int base = b * SCB + t * 8;
    #pragma unroll
    for (int i = 0; i < 8; ++i) { int idx = base + i; s += (idx < Nout) ? cnt[idx] : 0; }
    ts[t] = s;
    __syncthreads();
    if (t == 0) { int r = 0; for (int i = 0; i < 256; ++i) r += ts[i]; psums[b] = r; }
}

__global__ __launch_bounds__(256) void scan_psums(int* __restrict__ psums, int nb) {
    __shared__ int ts[256];
    const int t = threadIdx.x;
    const int chunk = (nb + 255) / 256;
    const int b0 = t * chunk;
    int s = 0;
    for (int i = 0; i < chunk; ++i) { int idx = b0 + i; if (idx < nb) s += psums[idx]; }
    ts[t] = s;
    __syncthreads();
    if (t == 0) { int r = 0; for (int i = 0; i < 256; ++i) { int v = ts[i]; ts[i] = r; r += v; } }
    __syncthreads();
    int run = ts[t];
    for (int i = 0; i < chunk; ++i) {
        int idx = b0 + i;
        if (idx < nb) { int v = psums[idx]; psums[idx] = run; run += v; }
    }
}

__global__ __launch_bounds__(256) void scan_write(const int* __restrict__ cnt,
                                                  const int* __restrict__ psums,
                                                  int* __restrict__ rowptr,
                                                  int* __restrict__ cursor, int Nout) {
    __shared__ int ts[256];
    const int b = blockIdx.x, t = threadIdx.x;
    const int base = b * SCB + t * 8;
    int c[8]; int s = 0;
    #pragma unroll
    for (int i = 0; i < 8; ++i) { int idx = base + i; c[i] = (idx < Nout) ? cnt[idx] : 0; s += c[i]; }
    ts[t] = s;
    __syncthreads();
    if (t == 0) { int r = 0; for (int i = 0; i < 256; ++i) { int v = ts[i]; ts[i] = r; r += v; } }
    __syncthreads();
    int run = psums[b] + ts[t];
    #pragma unroll
    for (int i = 0; i < 8; ++i) {
        int idx = base + i;
        if (idx < Nout) { rowptr[idx] = run; cursor[idx] = run; run += c[i]; }
    }
}

// ent[pos] = pp*27+k  (pp = perm position == buf slot base)
__global__ __launch_bounds__(256) void fill_ent(const int* __restrict__ oidx,
                                                const int* __restrict__ perm,
                                                int* __restrict__ cursor,
                                                int* __restrict__ ent, int Npts) {
    for (int pp = blockIdx.x * 256 + threadIdx.x; pp < Npts; pp += gridDim.x * 256) {
        int p = perm[pp];
        #pragma unroll
        for (int k = 0; k < KVOL; ++k) {
            int o = oidx[p * KVOL + k];
            int pos = atomicAdd(&cursor[o], 1);
            ent[pos] = pp * KVOL + k;
        }
    }
}

// Stage bf16 A tile via permuted point ids.
__device__ __forceinline__ void stage_A_perm(const float* __restrict__ feats,
                                             const int* Pm,
                                             unsigned short* As, int base, int Npts) {
    const int tid = threadIdx.x;
    #pragma unroll
    for (int e = 0; e < 4; ++e) {
        int lin = e * 1024 + tid * 4;
        int row = lin >> 6, col = lin & 63;
        float4 v = make_float4(0.f, 0.f, 0.f, 0.f);
        if (base + row < Npts)
            v = *reinterpret_cast<const float4*>(feats + (size_t)Pm[row] * 64 + col);
        As[lin + 0] = f2bf(v.x);
        As[lin + 1] = f2bf(v.y);
        As[lin + 2] = f2bf(v.z);
        As[lin + 3] = f2bf(v.w);
    }
}

// ---------------------------------------------------------------------------
// conv_once: THE single conv pass. Perm order. Writes ALL contributions as
// bf16 to buf[(pp*27+k)*64 .. +64] (dense 221KB window/block => full-line
// evictions). Accumulates stats: s over all, q over single rows.
// No atomics on out, no fp32 scatter.
// ---------------------------------------------------------------------------
__global__ __launch_bounds__(256) void conv_once(const float* __restrict__ feats,
                                                 const unsigned short* __restrict__ wfrag,
                                                 const int* __restrict__ oidx,
                                                 const int* __restrict__ cnt,
                                                 const int* __restrict__ perm,
                                                 unsigned short* __restrict__ buf,
                                                 float* __restrict__ stats,
                                                 int Npts) {
    __shared__ unsigned short As[64 * 64];
    __shared__ int Is[64 * KVOL];          // sign bit = multi flag
    __shared__ unsigned short Ws[KG * 4096];
    __shared__ float red[16 * 32];
    __shared__ int Pm[64];

    const int tid  = threadIdx.x;
    const int base = blockIdx.x * 64;

    if (tid < 64) Pm[tid] = (base + tid < Npts) ? perm[base + tid] : 0;
    __syncthreads();

    stage_A_perm(feats, Pm, As, base, Npts);
    for (int lin = tid; lin < 64 * KVOL; lin += 256) {
        int row = lin / KVOL, k = lin - row * KVOL;
        int iv = 0;
        if (base + row < Npts) {
            int o = oidx[Pm[row] * KVOL + k];
            iv = (cnt[o] > 1) ? 0x80000000 : 0;
        }
        Is[lin] = iv;
    }
    __syncthreads();

    const int w = tid >> 6, l = tid & 63, cl = l & 15, hi = l >> 4;
    const bool valid = (base + 16 * w + cl) < Npts;
    const v8bf a0 = *reinterpret_cast<const v8bf*>(&As[(16 * w + cl) * 64 + hi * 8]);
    const v8bf a1 = *reinterpret_cast<const v8bf*>(&As[(16 * w + cl) * 64 + 32 + hi * 8]);
    const v8bf* wfv = reinterpret_cast<const v8bf*>(wfrag);
    v8bf*       Wv  = reinterpret_cast<v8bf*>(Ws);
    const v8bf* Wl  = reinterpret_cast<const v8bf*>(Ws);

    unsigned short* browbase = buf + ((size_t)(base + 16 * w + cl) * KVOL) * 64;

    f32x4 s4[4], q4[4];
    #pragma unroll
    for (int t = 0; t < 4; ++t) { s4[t] = (f32x4){0.f,0.f,0.f,0.f}; q4[t] = (f32x4){0.f,0.f,0.f,0.f}; }

    for (int k0 = 0; k0 < KVOL; k0 += KG) {
        const int kn = (KVOL - k0) < KG ? (KVOL - k0) : KG;
        __syncthreads();
        for (int j = tid; j < kn * 512; j += 256)
            Wv[j] = wfv[k0 * 512 + j];
        __syncthreads();

        for (int dk = 0; dk < kn; ++dk) {
            const int k = k0 + dk;
            f32x4 acc[4];
            #pragma unroll
            for (int t = 0; t < 4; ++t) acc[t] = (f32x4){0.f, 0.f, 0.f, 0.f};
            #pragma unroll
            for (int t = 0; t < 4; ++t) {
                v8bf b0 = Wl[((dk * 4 + t) * 2 + 0) * 64 + l];
                v8bf b1 = Wl[((dk * 4 + t) * 2 + 1) * 64 + l];
                acc[t] = __builtin_amdgcn_mfma_f32_16x16x32_bf16(b0, a0, acc[t], 0, 0, 0);
                acc[t] = __builtin_amdgcn_mfma_f32_16x16x32_bf16(b1, a1, acc[t], 0, 0, 0);
            }
            if (valid) {
                int iv = Is[(16 * w + cl) * KVOL + k];
                unsigned short* brow = browbase + (size_t)k * 64;
                #pragma unroll
                for (int t = 0; t < 4; ++t) {
                    s4[t] += acc[t];
                    us4 u;
                    #pragma unroll
                    for (int j = 0; j < 4; ++j) u[j] = f2bf(acc[t][j]);
                    *reinterpret_cast<us4*>(brow + t * 16 + hi * 4) = u;
                }
                if (iv >= 0) {
                    #pragma unroll
                    for (int t = 0; t < 4; ++t) q4[t] += acc[t] * acc[t];
                }
            }
        }
    }

    #pragma unroll
    for (int m = 1; m < 16; m <<= 1) {
        #pragma unroll
        for (int t = 0; t < 4; ++t)
            #pragma unroll
            for (int j = 0; j < 4; ++j) {
                s4[t][j] += __shfl_xor(s4[t][j], m, 16);
                q4[t][j] += __shfl_xor(q4[t][j], m, 16);
            }
    }
    if (cl == 0) {
        int g = w * 4 + hi;
        #pragma unroll
        for (int t = 0; t < 4; ++t)
            #pragma unroll
            for (int j = 0; j < 4; ++j) {
                red[g * 32 + t * 4 + j]      = s4[t][j];
                red[g * 32 + 16 + t * 4 + j] = q4[t][j];
            }
    }
    __syncthreads();
    if (tid < 64) {   // channel = t*16 + h*4 + j
        int t = tid >> 4, h = (tid >> 2) & 3, j = tid & 3;
        float ss = 0.f, qq = 0.f;
        #pragma unroll
        for (int ww = 0; ww < 4; ++ww) {
            ss += red[(ww * 4 + h) * 32 + t * 4 + j];
            qq += red[(ww * 4 + h) * 32 + 16 + t * 4 + j];
        }
        unsafeAtomicAdd(&stats[tid],      ss);
        unsafeAtomicAdd(&stats[64 + tid], qq);
    }
}

// ---------------------------------------------------------------------------
// multi_merge: for multi rows, sum their bf16 contributions from buf (via
// CSR), write fp32 sum to out[r], add sum^2 to q-stats. Reversed row order
// for L3 hit on recently-written buf.
// ---------------------------------------------------------------------------
__global__ __launch_bounds__(256) void multi_merge(const unsigned short* __restrict__ buf,
                                                   const int* __restrict__ cnt,
                                                   const int* __restrict__ rowptr,
                                                   const int* __restrict__ ent,
                                                   float* __restrict__ out,
                                                   float* __restrict__ stats, int Nout) {
    __shared__ int ShC[64], ShSt[64];
    __shared__ float redq[64 * 64];
    const int tid = threadIdx.x;
    const int i = tid >> 2, j = tid & 3;
    const int nchunk = (Nout + 63) / 64;

    f32x4 q[4];
    #pragma unroll
    for (int t = 0; t < 4; ++t) q[t] = (f32x4){0.f, 0.f, 0.f, 0.f};

    for (int c = nchunk - 1 - blockIdx.x; c >= 0; c -= gridDim.x) {
        long r0 = (long)c * 64;
        __syncthreads();
        if (tid < 64) {
            long r = r0 + tid;
            ShC[tid]  = (r < Nout) ? cnt[r] : 0;
            ShSt[tid] = (r < Nout) ? rowptr[r] : 0;
        }
        __syncthreads();
        int cc = ShC[i];
        if (cc > 1) {
            long r = r0 + i;
            int st = ShSt[i];
            f32x4 s[4];
            #pragma unroll
            for (int t = 0; t < 4; ++t) s[t] = (f32x4){0.f, 0.f, 0.f, 0.f};
            for (int e = 0; e < cc; ++e) {
                int slot = ent[st + e];
                const unsigned short* br = buf + (size_t)slot * 64 + j * 16;
                us8 u0 = *reinterpret_cast<const us8*>(br);
                us8 u1 = *reinterpret_cast<const us8*>(br + 8);
                #pragma unroll
                for (int t = 0; t < 2; ++t)
                    #pragma unroll
                    for (int jj = 0; jj < 4; ++jj) {
                        s[t][jj]     += bf2f(u0[t * 4 + jj]);
                        s[2 + t][jj] += bf2f(u1[t * 4 + jj]);
                    }
            }
            float* dst = out + (size_t)r * 64 + j * 16;
            #pragma unroll
            for (int t = 0; t < 4; ++t) {
                *reinterpret_cast<f32x4*>(dst + t * 4) = s[t];
                q[t] += s[t] * s[t];
            }
        }
    }

    __syncthreads();
    #pragma unroll
    for (int t = 0; t < 4; ++t)
        #pragma unroll
        for (int jj = 0; jj < 4; ++jj)
            redq[i * 64 + j * 16 + t * 4 + jj] = q[t][jj];
    __syncthreads();
    if (tid < 64) {
        float s = 0.f;
        for (int ii = 0; ii < 64; ++ii) s += redq[ii * 64 + tid];
        unsafeAtomicAdd(&stats[64 + tid], s);
    }
}

// ---------------------------------------------------------------------------
// final_apply: row-major (reversed) BN+LeakyReLU. Single rows gather their
// one bf16 contribution from buf; multi rows read fp32 sum from out.
// Sequential fp32 stores.
// ---------------------------------------------------------------------------
__global__ __launch_bounds__(256) void final_apply(const unsigned short* __restrict__ buf,
                                                   const int* __restrict__ cnt,
                                                   const int* __restrict__ rowptr,
                                                   const int* __restrict__ ent,
                                                   const float* __restrict__ stats,
                                                   const float* __restrict__ gamma,
                                                   const float* __restrict__ beta,
                                                   float* __restrict__ out, int Nout) {
    __shared__ int ShS[64];
    const int tid = threadIdx.x, i = tid >> 2, j = tid & 3;
    const float inv = 1.0f / (float)Nout;

    f32x4 sc[4], sh[4];
    #pragma unroll
    for (int t = 0; t < 4; ++t) {
        int c0 = j * 16 + t * 4;
        f32x4 m4 = *reinterpret_cast<const f32x4*>(stats + c0);
        f32x4 v4 = *reinterpret_cast<const f32x4*>(stats + 64 + c0);
        f32x4 g4 = *reinterpret_cast<const f32x4*>(gamma + c0);
        f32x4 b4 = *reinterpret_cast<const f32x4*>(beta + c0);
        #pragma unroll
        for (int jj = 0; jj < 4; ++jj) {
            float m   = m4[jj] * inv;
            float var = v4[jj] * inv - m * m;
            float scv = g4[jj] * rsqrtf(var + 1e-5f);
            sc[t][jj] = scv;
            sh[t][jj] = b4[jj] - scv * m;
        }
    }

    const int nchunk = (Nout + 63) / 64;
    for (int c = nchunk - 1 - blockIdx.x; c >= 0; c -= gridDim.x) {
        long r0 = (long)c * 64;
        __syncthreads();
        if (tid < 64) {
            long r = r0 + tid;
            int sv = -1;                         // -1 => OOB, skip
            if (r < Nout) {
                int cc = cnt[r];
                sv = (cc == 1) ? ent[rowptr[r]] : -2;   // -2 => multi (read out)
            }
            ShS[tid] = sv;
        }
        __syncthreads();
        long r = r0 + i;
        int sv = ShS[i];
        if (r < Nout && sv != -1) {
            f32x4 v[4];
            if (sv >= 0) {
                const unsigned short* br = buf + (size_t)sv * 64 + j * 16;
                us8 u0 = *reinterpret_cast<const us8*>(br);
                us8 u1 = *reinterpret_cast<const us8*>(br + 8);
                #pragma unroll
                for (int t = 0; t < 2; ++t)
                    #pragma unroll
                    for (int jj = 0; jj < 4; ++jj) {
                        v[t][jj]     = bf2f(u0[t * 4 + jj]);
                        v[2 + t][jj] = bf2f(u1[t * 4 + jj]);
                    }
            } else {
                const float* srcp = out + (size_t)r * 64 + j * 16;
                #pragma unroll
                for (int t = 0; t < 4; ++t) v[t] = *reinterpret_cast<const f32x4*>(srcp + t * 4);
            }
            float* dst = out + (size_t)r * 64 + j * 16;
            #pragma unroll
            for (int t = 0; t < 4; ++t) {
                f32x4 y = v[t] * sc[t] + sh[t];
                #pragma unroll
                for (int jj = 0; jj < 4; ++jj) y[jj] = y[jj] > 0.f ? y[jj] : 0.01f * y[jj];
                *reinterpret_cast<f32x4*>(dst + t * 4) = y;
            }
        }
    }
}

// ---------------------------------------------------------------------------
// Fallback path (round-1 structure).
// ---------------------------------------------------------------------------
__global__ __launch_bounds__(256) void conv_scatter_fb(const float* __restrict__ feats,
                                                       const unsigned short* __restrict__ wfrag,
                                                       const int* __restrict__ oidx,
                                                       float* __restrict__ out,
                                                       int Npts) {
    __shared__ unsigned short As[64 * 64];
    __shared__ int Is[64 * KVOL];
    const int tid  = threadIdx.x;
    const int base = blockIdx.x * 64;
    #pragma unroll
    for (int e = 0; e < 4; ++e) {
        int lin = e * 1024 + tid * 4;
        int row = lin >> 6, col = lin & 63;
        float4 v = make_float4(0.f, 0.f, 0.f, 0.f);
        if (base + row < Npts)
            v = *reinterpret_cast<const float4*>(feats + (size_t)(base + row) * 64 + col);
        As[lin + 0] = f2bf(v.x); As[lin + 1] = f2bf(v.y);
        As[lin + 2] = f2bf(v.z); As[lin + 3] = f2bf(v.w);
    }
    for (int lin = tid; lin < 64 * KVOL; lin += 256) {
        int g = base * KVOL + lin;
        Is[lin] = (g < Npts * KVOL) ? oidx[g] : 0;
    }
    __syncthreads();
    const int w = tid >> 6, l = tid & 63, cl = l & 15, hi = l >> 4;
    const v8bf a0 = *reinterpret_cast<const v8bf*>(&As[(16 * w + cl) * 64 + hi * 8]);
    const v8bf a1 = *reinterpret_cast<const v8bf*>(&As[(16 * w + cl) * 64 + 32 + hi * 8]);
    const v8bf* wf = reinterpret_cast<const v8bf*>(wfrag);
    for (int k = 0; k < KVOL; ++k) {
        f32x4 acc[4];
        #pragma unroll
        for (int t = 0; t < 4; ++t) acc[t] = (f32x4){0.f, 0.f, 0.f, 0.f};
        #pragma unroll
        for (int t = 0; t < 4; ++t) {
            v8bf b0 = wf[((k * 4 + t) * 2 + 0) * 64 + l];
            v8bf b1 = wf[((k * 4 + t) * 2 + 1) * 64 + l];
            acc[t] = __builtin_amdgcn_mfma_f32_16x16x32_bf16(b0, a0, acc[t], 0, 0, 0);
            acc[t] = __builtin_amdgcn_mfma_f32_16x16x32_bf16(b1, a1, acc[t], 0, 0, 0);
        }
        if ((base + 16 * w + cl) < Npts) {
            int o = Is[(16 * w + cl) * KVOL + k];
            float* dst = out + (size_t)o * 64 + hi * 4;
            #pragma unroll
            for (int t = 0; t < 4; ++t)
                #pragma unroll
                for (int j = 0; j < 4; ++j)
                    unsafeAtomicAdd(dst + t * 16 + j, acc[t][j]);
        }
    }
}

__global__ __launch_bounds__(256) void bn_stats(const float* __restrict__ out,
                                                float* __restrict__ stats,
                                                int Nout) {
    const int tid = threadIdx.x;
    const int cg  = tid & 15;
    const int rs  = tid >> 4;
    f32x4 s = {0.f, 0.f, 0.f, 0.f}, q = {0.f, 0.f, 0.f, 0.f};
    for (long r = (long)blockIdx.x * 16 + rs; r < Nout; r += (long)gridDim.x * 16) {
        f32x4 v = *reinterpret_cast<const f32x4*>(out + (size_t)r * 64 + cg * 4);
        s += v;
        q += v * v;
    }
    __shared__ f32x4 sd[256];
    __shared__ f32x4 qd[256];
    sd[tid] = s; qd[tid] = q;
    __syncthreads();
    #pragma unroll
    for (int st = 8; st >= 1; st >>= 1) {
        if (rs < st) { sd[tid] += sd[tid + 16 * st]; qd[tid] += qd[tid + 16 * st]; }
        __syncthreads();
    }
    if (rs == 0) {
        #pragma unroll
        for (int c = 0; c < 4; ++c) {
            unsafeAtomicAdd(&stats[cg * 4 + c],      sd[tid][c]);
            unsafeAtomicAdd(&stats[64 + cg * 4 + c], qd[tid][c]);
        }
    }
}

__global__ __launch_bounds__(256) void bn_apply(float* __restrict__ out,
                                                const float* __restrict__ stats,
                                                const float* __restrict__ gamma,
                                                const float* __restrict__ beta,
                                                int Nout) {
    const int tid = threadIdx.x;
    const int cg  = tid & 15;
    const int rs  = tid >> 4;
    const float inv = 1.0f / (float)Nout;
    f32x4 scale, shift;
    #pragma unroll
    for (int c = 0; c < 4; ++c) {
        float m   = stats[cg * 4 + c] * inv;
        float var = stats[64 + cg * 4 + c] * inv - m * m;
        float sc  = gamma[cg * 4 + c] * rsqrtf(var + 1e-5f);
        scale[c]  = sc;
        shift[c]  = beta[cg * 4 + c] - sc * m;
    }
    for (long r = (long)blockIdx.x * 16 + rs; r < Nout; r += (long)gridDim.x * 16) {
        f32x4* p = reinterpret_cast<f32x4*>(out + (size_t)r * 64 + cg * 4);
        f32x4 v = *p;
        v = v * scale + shift;
        #pragma unroll
        for (int c = 0; c < 4; ++c) v[c] = v[c] > 0.f ? v[c] : 0.01f * v[c];
        *p = v;
    }
}

static inline size_t al4k(size_t x) { return (x + 4095) & ~(size_t)4095; }

extern "C" void kernel_launch(void* const* d_in, const int* in_sizes, int n_in,
                              void* d_out, int out_size, void* d_ws, size_t ws_size,
                              hipStream_t stream) {
    const float* feats = (const float*)d_in[1];
    const float* W     = (const float*)d_in[2];
    const float* gamma = (const float*)d_in[3];
    const float* beta  = (const float*)d_in[4];
    const int*   oidx  = (const int*)d_in[5];
    float* out = (float*)d_out;

    const int Npts = in_sizes[1] / 64;   // 100000
    const int Nout = out_size / 64;      // ~2.51M
    const int M    = Npts * KVOL;
    const int nb   = (Nout + SCB - 1) / SCB;

    // Workspace layout
    char* ws = (char*)d_ws;
    float* stats = (float*)ws;                                   // 512 B
    unsigned short* wfrag = (unsigned short*)(ws + 4096);        // 216 KiB
    int* hist = (int*)(ws + 262144);                             // 64 KiB
    int* perm = (int*)(ws + 327680);                             // Npts*4
    size_t o1 = al4k(327680 + (size_t)Npts * 4);
    int* cnt    = (int*)(ws + o1);
    size_t o2 = al4k(o1 + (size_t)Nout * 4);
    int* rowptr = (int*)(ws + o2);
    size_t o3 = al4k(o2 + (size_t)Nout * 4);
    int* cursor = (int*)(ws + o3);
    size_t o4 = al4k(o3 + (size_t)Nout * 4);
    int* psums  = (int*)(ws + o4);
    size_t o5 = al4k(o4 + (size_t)nb * 4);
    int* ent    = (int*)(ws + o5);
    size_t o6 = al4k(o5 + (size_t)M * 4);
    unsigned short* buf = (unsigned short*)(ws + o6);
    const size_t ws_need = o6 + (size_t)M * 128;

    const int cgrid = (Npts + 63) / 64;
    const int pgrid = (Npts + 255) / 256;

    if (ws_size >= ws_need) {
        hipMemsetAsync(hist, 0, NBKT * sizeof(int), stream);
        hipMemsetAsync(cnt, 0, (size_t)Nout * sizeof(int), stream);
        hipLaunchKernelGGL(prep_kernel, dim3(432), dim3(256), 0, stream, W, wfrag, stats);
        hipLaunchKernelGGL(hist_kernel, dim3(pgrid), dim3(256), 0, stream, oidx, hist, Npts, Nout);
        hipLaunchKernelGGL(count_kernel, dim3(2048), dim3(256), 0, stream, oidx, cnt, M);
        hipLaunchKernelGGL(scan_hist, dim3(1), dim3(256), 0, stream, hist);
        hipLaunchKernelGGL(perm_fill, dim3(pgrid), dim3(256), 0, stream, oidx, hist, perm, Npts, Nout);
        hipLaunchKernelGGL(scan_part, dim3(nb), dim3(256), 0, stream, cnt, psums, Nout);
        hipLaunchKernelGGL(scan_psums, dim3(1), dim3(256), 0, stream, psums, nb);
        hipLaunchKernelGGL(scan_write, dim3(nb), dim3(256), 0, stream, cnt, psums, rowptr, cursor, Nout);
        hipLaunchKernelGGL(fill_ent, dim3(pgrid), dim3(256), 0, stream, oidx, perm, cursor, ent, Npts);
        hipLaunchKernelGGL(conv_once, dim3(cgrid), dim3(256), 0, stream,
                           feats, wfrag, oidx, cnt, perm, buf, stats, Npts);
        hipLaunchKernelGGL(multi_merge, dim3(2048), dim3(256), 0, stream,
                           buf, cnt, rowptr, ent, out, stats, Nout);
        hipLaunchKernelGGL(final_apply, dim3(2048), dim3(256), 0, stream,
                           buf, cnt, rowptr, ent, stats, gamma, beta, out, Nout);
    } else {
        hipMemsetAsync(d_out, 0, (size_t)out_size * sizeof(float), stream);
        hipLaunchKernelGGL(prep_kernel, dim3(432), dim3(256), 0, stream, W, wfrag, stats);
        hipLaunchKernelGGL(conv_scatter_fb, dim3(cgrid), dim3(256), 0, stream,
                           feats, wfrag, oidx, out, Npts);
        hipLaunchKernelGGL(bn_stats, dim3(2048), dim3(256), 0, stream, out, stats, Nout);
        hipLaunchKernelGGL(bn_apply, dim3(2048), dim3(256), 0, stream, out, stats, gamma, beta, Nout);
    }
}